// Round 3
// baseline (233.147 us; speedup 1.0000x reference)
//
#include <hip/hip_runtime.h>
#include <math.h>

// ive(v=49.5, z) = exp(-z) * I_v(z) via the uniform (Debye) asymptotic
// expansion DLMF 10.41.3, log2-domain, gfx950 hardware transcendentals.
// See R1/R2 notes: OCML logf/expf removal took kernel 88.7 -> ~74 us, but
// counters imply neither VALU-issue (~23 us) nor HBM BW (~32 us) binds —
// the single 1KB-load-per-wave structure is memory-LATENCY bound.
// R3 change: 4 independent float4 loads per thread (4x MLP per wave,
// 4x launch amortization), coalesced via grid-sized stride g.

__device__ __forceinline__ float ive_debye(float z) {
    const float inv_v    = (float)(1.0 / 49.5);
    const float c_pref   = 0.05670319f;                  // 1/sqrt(2*pi*49.5)
    const float v_log2e  = 71.41340452f;                 // 49.5 * log2(e)
    const float n_log2e  = -1.4426950408889634f;         // -log2(e)
    const float c1 = (float)(1.0 / (24.0 * 49.5));
    const float c2 = (float)(1.0 / (1152.0 * 49.5 * 49.5));
    const float c3 = (float)(1.0 / (414720.0 * 49.5 * 49.5 * 49.5));
    const float c4 = (float)(1.0 / (39813120.0 * 49.5 * 49.5 * 49.5 * 49.5));

    float x = z * inv_v;
    float q = fmaf(x, x, 1.0f);
    float t = __builtin_amdgcn_rsqf(q);        // 1/sqrt(1+x^2)
    float p = q * t;                            // sqrt(1+x^2)
    float s = t * t;

    float lg = __builtin_amdgcn_logf(x * __builtin_amdgcn_rcpf(1.0f + p));
    float e2 = fmaf(v_log2e, p, fmaf(49.5f, lg, n_log2e * z));

    float u1 = c1 * t * fmaf(-5.0f, s, 3.0f);
    float u2 = c2 * s * fmaf(s, fmaf(385.0f, s, -462.0f), 81.0f);
    float u3 = c3 * (t * s) *
               fmaf(s, fmaf(s, fmaf(-425425.0f, s, 765765.0f), -369603.0f), 30375.0f);
    float u4 = c4 * (s * s) *
               fmaf(s, fmaf(s, fmaf(s, fmaf(185910725.0f, s, -446185740.0f),
                                    349922430.0f), -94121676.0f), 4465125.0f);
    float poly = 1.0f + u1 + u2 + u3 + u4;

    float pref = c_pref * __builtin_amdgcn_sqrtf(t);
    return __builtin_amdgcn_exp2f(e2) * pref * poly;
}

__device__ __forceinline__ float4 ive4(float4 zv) {
    float4 o;
    o.x = ive_debye(zv.x);
    o.y = ive_debye(zv.y);
    o.z = ive_debye(zv.z);
    o.w = ive_debye(zv.w);
    return o;
}

// m = number of float4 elements; g = thread count (stride). Each thread
// loads indices t, t+g, t+2g, t+3g — 4 independent coalesced 16B loads
// in flight before any compute.
__global__ __launch_bounds__(256) void ive_kernel(const float4* __restrict__ z,
                                                  float4* __restrict__ out,
                                                  int m, int g,
                                                  const float* __restrict__ zs,
                                                  float* __restrict__ outs, int n) {
    int t = blockIdx.x * blockDim.x + threadIdx.x;
    int i0 = t;
    int i1 = t + g;
    int i2 = t + 2 * g;
    int i3 = t + 3 * g;
    float4 a, b, c, d;
    bool p0 = i0 < m, p1 = i1 < m, p2 = i2 < m, p3 = i3 < m;
    if (p0) a = z[i0];
    if (p1) b = z[i1];
    if (p2) c = z[i2];
    if (p3) d = z[i3];
    if (p0) out[i0] = ive4(a);
    if (p1) out[i1] = ive4(b);
    if (p2) out[i2] = ive4(c);
    if (p3) out[i3] = ive4(d);
    // scalar tail (n % 4 != 0)
    if (t == 0) {
        for (int j = m * 4; j < n; ++j) outs[j] = ive_debye(zs[j]);
    }
}

extern "C" void kernel_launch(void* const* d_in, const int* in_sizes, int n_in,
                              void* d_out, int out_size, void* d_ws, size_t ws_size,
                              hipStream_t stream) {
    const float* z = (const float*)d_in[0];
    float* out = (float*)d_out;
    int n = in_sizes[0];
    int m = n >> 2;                       // float4 count
    int g = (m + 3) >> 2;                 // threads; each does 4 float4s
    int threads = 256;
    int blocks = (g + threads - 1) / threads;
    if (blocks < 1) blocks = 1;
    g = blocks * threads;                 // actual stride = launched threads
    ive_kernel<<<blocks, threads, 0, stream>>>((const float4*)z, (float4*)out,
                                               m, g, z, out, n);
}

// Round 4
// 220.222 us; speedup vs baseline: 1.0587x; 1.0587x over previous
//
#include <hip/hip_runtime.h>
#include <math.h>

// ive(v=49.5, z) = exp(-z) * I_v(z) via the uniform (Debye) asymptotic
// expansion DLMF 10.41.3, log2-domain, gfx950 hardware transcendentals.
//
// R3 post-mortem: 4x-MLP unroll regressed (73 -> 88 us) => not latency-bound.
// Model: per-wave load-wait -> compute -> store-drain serializes; time ~
// mem_floor(42 us @ 6.3 TB/s for 268 MB) + VALU(23.5 us). So R4 trims VALU:
// drop u2..u4 Debye corrections (<= 3e-7 relative where the value is near
// max — absolute ~1e-13, threshold is 4.32e-9) keeping only u1; body is now
// ~15 full-rate + 5 quarter-rate ops/element. Nontemporal stores keep the
// write stream from evicting the z stream in L2/L3.

typedef float vfloat4 __attribute__((ext_vector_type(4)));

__device__ __forceinline__ float ive_debye(float z) {
    const float inv_v    = (float)(1.0 / 49.5);
    const float c_pref   = 0.05670319f;                  // 1/sqrt(2*pi*49.5)
    const float v_log2e  = 71.41340452f;                 // 49.5 * log2(e)
    const float n_log2e  = -1.4426950408889634f;         // -log2(e)
    const float c1       = (float)(1.0 / (24.0 * 49.5));

    float x = z * inv_v;
    float q = fmaf(x, x, 1.0f);
    float t = __builtin_amdgcn_rsqf(q);        // (1+x^2)^{-1/2}
    float p = q * t;                            // (1+x^2)^{+1/2}
    float s = t * t;

    float lg = __builtin_amdgcn_logf(x * __builtin_amdgcn_rcpf(1.0f + p));
    float e2 = fmaf(v_log2e, p, fmaf(49.5f, lg, n_log2e * z));

    // poly = 1 + u1(t)/v  (u2..u4 dropped: <=3e-7 relative where it matters)
    float poly = fmaf(c1 * t, fmaf(-5.0f, s, 3.0f), 1.0f);

    float pref = c_pref * __builtin_amdgcn_sqrtf(t);    // (1+x^2)^{-1/4} / sqrt(2 pi v)
    return __builtin_amdgcn_exp2f(e2) * pref * poly;
}

__global__ __launch_bounds__(256) void ive_kernel(const vfloat4* __restrict__ z,
                                                  vfloat4* __restrict__ out,
                                                  int m,
                                                  const float* __restrict__ zs,
                                                  float* __restrict__ outs, int n) {
    int i = blockIdx.x * blockDim.x + threadIdx.x;
    if (i < m) {
        vfloat4 zv = z[i];
        vfloat4 o;
        o.x = ive_debye(zv.x);
        o.y = ive_debye(zv.y);
        o.z = ive_debye(zv.z);
        o.w = ive_debye(zv.w);
        __builtin_nontemporal_store(o, &out[i]);
    }
    // scalar tail (n % 4 != 0) — never taken for 4096x8192 but kept correct
    if (i == 0) {
        for (int j = m * 4; j < n; ++j) outs[j] = ive_debye(zs[j]);
    }
}

extern "C" void kernel_launch(void* const* d_in, const int* in_sizes, int n_in,
                              void* d_out, int out_size, void* d_ws, size_t ws_size,
                              hipStream_t stream) {
    const float* z = (const float*)d_in[0];
    float* out = (float*)d_out;
    int n = in_sizes[0];
    int m = n >> 2;
    int threads = 256;
    int blocks = (m + threads - 1) / threads;
    if (blocks < 1) blocks = 1;
    ive_kernel<<<blocks, threads, 0, stream>>>((const vfloat4*)z, (vfloat4*)out,
                                               m, z, out, n);
}